// Round 1
// baseline (14773.103 us; speedup 1.0000x reference)
//
#include <hip/hip_runtime.h>
#include <math.h>

#define ND 64
#define PAD 65
#define NN 4096
#define NB 8192

// ws layout (floats)
#define OFF_MEANPART ((size_t)0)        // 32*4096
#define OFF_MEANA    ((size_t)131072)
#define OFF_S        ((size_t)135168)
#define OFF_SI       ((size_t)139264)
#define OFF_SS       ((size_t)143360)
#define OFF_TBAR     ((size_t)147456)
#define OFF_MI       ((size_t)151552)
#define OFF_P        ((size_t)155648)
#define OFF_VARPART  ((size_t)155712)   // 1024
#define OFF_LAM      ((size_t)156736)   // NB*ND = 524288
#define OFF_TPART    ((size_t)681024)   // G2*4096

// ---------------------------------------------------------------------------
// Two-sided LDS Jacobi (256 threads, one 64x64 matrix). Used for the few
// single-matrix eighs (mean, shift, tbar, mean2). Circle-method parallel
// ordering, relative+absolute rotation threshold, converges when a full sweep
// applies zero rotations.
// ---------------------------------------------------------------------------
__device__ void jacobi2s(float (&A)[ND][PAD], float (&V)[ND][PAD], int tid) {
  __shared__ float cs_[32], sn_[32];
  __shared__ int   pp_[32], qq_[32];
  __shared__ int   rotcnt_;
  __shared__ float fro2_;
  __shared__ float red_[4];

  __syncthreads();
  // Frobenius norm^2 of initial A (for absolute rotation floor)
  float loc = 0.f;
  for (int e = tid; e < NN; e += 256) { float a = A[e >> 6][e & 63]; loc += a * a; }
  for (int o = 32; o; o >>= 1) loc += __shfl_down(loc, o);
  if ((tid & 63) == 0) red_[tid >> 6] = loc;
  __syncthreads();
  if (tid == 0) fro2_ = red_[0] + red_[1] + red_[2] + red_[3];
  __syncthreads();
  float fro2 = fro2_;

  for (int sweep = 0; sweep < 20; ++sweep) {
    if (tid == 0) rotcnt_ = 0;
    __syncthreads();
    for (int r = 0; r < 63; ++r) {
      if (tid < 32) {
        int p, q;
        if (tid == 0) { p = 63; q = r; }
        else { p = (r + tid) % 63; q = (r + 63 - tid) % 63; }
        if (p > q) { int t0 = p; p = q; q = t0; }
        pp_[tid] = p; qq_[tid] = q;
        float app = A[p][p], aqq = A[q][q], apq = A[p][q];
        float thr = fmaxf(1e-12f * fabsf(app * aqq), 1e-14f * fro2);
        float c = 1.f, s = 0.f;
        if (apq * apq > thr) {
          float tau = (aqq - app) / (2.f * apq);
          float t = 1.f / (fabsf(tau) + sqrtf(1.f + tau * tau));
          t = (tau < 0.f) ? -t : t;
          c = 1.f / sqrtf(1.f + t * t);
          s = t * c;
          atomicAdd(&rotcnt_, 1);
        }
        cs_[tid] = c; sn_[tid] = s;
      }
      __syncthreads();
      // row pass: A <- J^T A
      for (int t = tid; t < 2048; t += 256) {
        int k = t >> 6, j = t & 63;
        int p = pp_[k], q = qq_[k]; float c = cs_[k], s = sn_[k];
        float ap = A[p][j], aq = A[q][j];
        A[p][j] = c * ap - s * aq;
        A[q][j] = s * ap + c * aq;
      }
      __syncthreads();
      // col pass on A (-> J^T A J) and V pass (V <- V J), independent
      for (int t = tid; t < 4096; t += 256) {
        int k = (t >> 6) & 31, j = t & 63;
        int p = pp_[k], q = qq_[k]; float c = cs_[k], s = sn_[k];
        if (t < 2048) {
          float ap = A[j][p], aq = A[j][q];
          A[j][p] = c * ap - s * aq;
          A[j][q] = s * ap + c * aq;
        } else {
          float vp = V[j][p], vq = V[j][q];
          V[j][p] = c * vp - s * vq;
          V[j][q] = s * vp + c * vq;
        }
      }
      __syncthreads();
    }
    int rc = rotcnt_;
    __syncthreads();
    if (rc == 0) break;
  }
}

// OUT_global[r*64+c] = sum_j f[j] * V[r][j] * V[c][j]   (256 threads)
__device__ void recon_write(const float (&V)[ND][PAD], const float* f, float* g,
                            int c, int wq) {
  float acc[16];
#pragma unroll
  for (int k = 0; k < 16; ++k) acc[k] = 0.f;
  for (int j = 0; j < ND; ++j) {
    float m = f[j] * V[c][j];
#pragma unroll
    for (int k = 0; k < 16; ++k) acc[k] = fmaf(V[wq + 4 * k][j], m, acc[k]);
  }
#pragma unroll
  for (int k = 0; k < 16; ++k) g[(wq + 4 * k) * ND + c] = acc[k];
}

// ---------------------------------------------------------------------------
// One-sided Jacobi, register-resident: one wave per matrix, lane = column.
// w[64] holds this lane's column of W (init W = A). XOR tournament ordering.
// On exit columns are mutually orthogonal to ~2e-5; sigma_j = ||w_j||,
// eigvec u_j = w_j / sigma_j (A SPD => lambda = sigma).
// ---------------------------------------------------------------------------
__device__ inline void jacobi1s(float (&w)[ND], int lane) {
  float g = 0.f;
#pragma unroll
  for (int i = 0; i < ND; ++i) g = fmaf(w[i], w[i], g);
  for (int sweep = 0; sweep < 18; ++sweep) {
    bool any = false;
    for (int r = 1; r < ND; ++r) {
      int partner = lane ^ r;
      float gv = __shfl(g, partner);
      float v[ND];
#pragma unroll
      for (int i = 0; i < ND; ++i) v[i] = __shfl(w[i], partner);
      float apq = 0.f;
#pragma unroll
      for (int i = 0; i < ND; ++i) apq = fmaf(w[i], v[i], apq);
      // identical bits in both partner lanes -> consistent decision
      if (apq * apq > 4e-10f * g * gv) {
        bool amP = lane < partner;
        float app = amP ? g : gv;
        float aqq = amP ? gv : g;
        float tau = (aqq - app) / (2.f * apq);
        float t = 1.f / (fabsf(tau) + sqrtf(1.f + tau * tau));
        t = (tau < 0.f) ? -t : t;
        float c = 1.f / sqrtf(1.f + t * t);
        float s = t * c;
        float s2 = amP ? -s : s;
#pragma unroll
        for (int i = 0; i < ND; ++i) w[i] = fmaf(s2, v[i], c * w[i]);
        float d = t * apq;
        g = amP ? (g - d) : (g + d);
        any = true;
      }
    }
    if (!__any(any)) break;
  }
}

// ---------------------------------------------------------------------------
// Kernels
// ---------------------------------------------------------------------------

// partial arithmetic mean over batch: part[32][4096]
__global__ __launch_bounds__(256) void k_mean_part(const float* __restrict__ x,
                                                   float* __restrict__ part) {
  int e = blockIdx.x * 256 + threadIdx.x;   // [0,4096)
  int chunk = blockIdx.y;                   // [0,32)
  const float* px = x + (size_t)chunk * 256 * NN + e;
  float s = 0.f;
  for (int i = 0; i < 256; ++i) s += px[(size_t)i * NN];
  part[(size_t)chunk * NN + e] = s;
}

__global__ __launch_bounds__(256) void k_mean_final(const float* __restrict__ part,
                                                    float* __restrict__ meanA) {
  int e = blockIdx.x * 256 + threadIdx.x;
  float s = 0.f;
  for (int c = 0; c < 32; ++c) s += part[(size_t)c * NN + e];
  meanA[e] = s * (1.f / (float)NB);
}

// block 0: eigh(meanA) -> s_out (mean^1/2), si_out (mean^-1/2)
// block 1: eigh(shift) -> ss_out (shift^1/2)
__global__ __launch_bounds__(256) void k_prep1(const float* __restrict__ meanA,
                                               const float* __restrict__ shift,
                                               float* __restrict__ s_out,
                                               float* __restrict__ si_out,
                                               float* __restrict__ ss_out) {
  __shared__ float A[ND][PAD], V[ND][PAD];
  __shared__ float f1[ND], f2[ND];
  int tid = threadIdx.x;
  const float* src = (blockIdx.x == 0) ? meanA : shift;
  for (int e = tid; e < NN; e += 256) A[e >> 6][e & 63] = src[e];
  for (int e = tid; e < NN; e += 256) V[e >> 6][e & 63] = ((e >> 6) == (e & 63)) ? 1.f : 0.f;
  jacobi2s(A, V, tid);
  if (tid < ND) {
    float wv = fmaxf(A[tid][tid], 1e-30f);
    f1[tid] = sqrtf(wv);
    f2[tid] = 1.f / sqrtf(wv);
  }
  __syncthreads();
  int c = tid & 63, wq = tid >> 6;
  if (blockIdx.x == 0) {
    recon_write(V, f1, s_out, c, wq);
    recon_write(V, f2, si_out, c, wq);
  } else {
    recon_write(V, f1, ss_out, c, wq);
  }
}

// batched Karcher tangent accumulation: per matrix M = si*x_i*si, eigh,
// t_i = U log(lam) U^T; per-block partial sum -> tPart[bid][4096]
__global__ __launch_bounds__(128, 2) void k_stage2(const float* __restrict__ x,
                                                   const float* __restrict__ si,
                                                   float* __restrict__ tPart,
                                                   int G2) {
  __shared__ float Xs[2][ND][PAD];
  __shared__ float lw_s[2][ND];
  int tid = threadIdx.x;
  int lane = tid & 63;
  int wv = tid >> 6;
  float (&X)[ND][PAD] = Xs[wv];
  int wid = blockIdx.x * 2 + wv;
  int nw = G2 * 2;

  float tacc[ND];
#pragma unroll
  for (int i2 = 0; i2 < ND; ++i2) tacc[i2] = 0.f;

  for (int i = wid; i < NB; i += nw) {
    // load x_i (lane = column)
    for (int r2 = 0; r2 < ND; ++r2) X[r2][lane] = x[(size_t)i * NN + r2 * ND + lane];
    // step1 (in place per-lane column): X <- si * X   (si symmetric)
    float w_[ND];
#pragma unroll
    for (int r2 = 0; r2 < ND; ++r2) w_[r2] = 0.f;
    for (int a = 0; a < ND; ++a) {
      float xa = X[a][lane];
#pragma unroll
      for (int r2 = 0; r2 < ND; ++r2) w_[r2] = fmaf(si[a * ND + r2], xa, w_[r2]);
    }
#pragma unroll
    for (int r2 = 0; r2 < ND; ++r2) X[r2][lane] = w_[r2];
    // step2: w = (si*x) * si  column `lane` -> registers
#pragma unroll
    for (int r2 = 0; r2 < ND; ++r2) w_[r2] = 0.f;
    for (int a = 0; a < ND; ++a) {
      float sa = si[a * ND + lane];
#pragma unroll
      for (int r2 = 0; r2 < ND; ++r2) w_[r2] = fmaf(X[r2][a], sa, w_[r2]);
    }
    jacobi1s(w_, lane);
    float s2 = 0.f;
#pragma unroll
    for (int r2 = 0; r2 < ND; ++r2) s2 = fmaf(w_[r2], w_[r2], s2);
    float sig = sqrtf(fmaxf(s2, 1e-38f));
    float inv = 1.f / sig;
    lw_s[wv][lane] = logf(sig);
#pragma unroll
    for (int r2 = 0; r2 < ND; ++r2) X[r2][lane] = w_[r2] * inv;  // U
    // accumulate t_i[r][lane] = sum_j log(lam_j) U[r][j] U[lane][j]
    for (int j = 0; j < ND; ++j) {
      float m = lw_s[wv][j] * X[lane][j];
#pragma unroll
      for (int r2 = 0; r2 < ND; ++r2) tacc[r2] = fmaf(X[r2][j], m, tacc[r2]);
    }
  }
  // combine the block's two waves, write one partial row
  if (wv == 1) {
#pragma unroll
    for (int r2 = 0; r2 < ND; ++r2) Xs[1][r2][lane] = tacc[r2];
  }
  __syncthreads();
  if (wv == 0) {
#pragma unroll
    for (int r2 = 0; r2 < ND; ++r2) tacc[r2] += Xs[1][r2][lane];
#pragma unroll
    for (int r2 = 0; r2 < ND; ++r2)
      tPart[(size_t)blockIdx.x * NN + r2 * ND + lane] = tacc[r2];
  }
}

__global__ __launch_bounds__(256) void k_reduce_t(const float* __restrict__ tPart,
                                                  float* __restrict__ tbar, int G2) {
  int e = blockIdx.x * 256 + threadIdx.x;
  float s = 0.f;
  for (int b = 0; b < G2; ++b) s += tPart[(size_t)b * NN + e];
  tbar[e] = s * (1.f / (float)NB);
}

// eigh(tbar) -> E=expm(tbar); mean2 = s*E*s; eigh(mean2) -> mi = mean2^-1/2
__global__ __launch_bounds__(256) void k_prep2(const float* __restrict__ tbar,
                                               const float* __restrict__ s_g,
                                               float* __restrict__ mi_out) {
  __shared__ float A[ND][PAD], V[ND][PAD];
  __shared__ float f1[ND];
  int tid = threadIdx.x;
  int c = tid & 63, wq = tid >> 6;
  for (int e = tid; e < NN; e += 256) A[e >> 6][e & 63] = tbar[e];
  for (int e = tid; e < NN; e += 256) V[e >> 6][e & 63] = ((e >> 6) == (e & 63)) ? 1.f : 0.f;
  jacobi2s(A, V, tid);
  if (tid < ND) f1[tid] = expf(A[tid][tid]);  // eigenvalues may be negative
  __syncthreads();
  // E into A (reads V,f1 only)
  {
    float acc[16];
#pragma unroll
    for (int k = 0; k < 16; ++k) acc[k] = 0.f;
    for (int j = 0; j < ND; ++j) {
      float m = f1[j] * V[c][j];
#pragma unroll
      for (int k = 0; k < 16; ++k) acc[k] = fmaf(V[wq + 4 * k][j], m, acc[k]);
    }
    __syncthreads();  // all V reads done before A overwritten? (A untouched) keep order
#pragma unroll
    for (int k = 0; k < 16; ++k) A[wq + 4 * k][c] = acc[k];
  }
  __syncthreads();
  // V <- s * E      (reads A, writes V; V dead)
  {
    float acc[16];
#pragma unroll
    for (int k = 0; k < 16; ++k) acc[k] = 0.f;
    for (int a = 0; a < ND; ++a) {
      float ea = A[a][c];
#pragma unroll
      for (int k = 0; k < 16; ++k) acc[k] = fmaf(s_g[(wq + 4 * k) * ND + a], ea, acc[k]);
    }
    __syncthreads();
#pragma unroll
    for (int k = 0; k < 16; ++k) V[wq + 4 * k][c] = acc[k];
  }
  __syncthreads();
  // A <- (s*E) * s  = mean2   (reads V, writes A)
  {
    float acc[16];
#pragma unroll
    for (int k = 0; k < 16; ++k) acc[k] = 0.f;
    for (int a = 0; a < ND; ++a) {
      float sa = s_g[a * ND + c];
#pragma unroll
      for (int k = 0; k < 16; ++k) acc[k] = fmaf(V[wq + 4 * k][a], sa, acc[k]);
    }
    __syncthreads();
#pragma unroll
    for (int k = 0; k < 16; ++k) A[wq + 4 * k][c] = acc[k];
  }
  __syncthreads();
  for (int e = tid; e < NN; e += 256) V[e >> 6][e & 63] = ((e >> 6) == (e & 63)) ? 1.f : 0.f;
  jacobi2s(A, V, tid);
  if (tid < ND) f1[tid] = 1.f / sqrtf(fmaxf(A[tid][tid], 1e-30f));
  __syncthreads();
  recon_write(V, f1, mi_out, c, wq);
}

// batched: W = mi*x_i*mi, eigh -> lam (ws), Aout = ss*U (d_out), var partials
__global__ __launch_bounds__(128, 2) void k_stage3(const float* __restrict__ x,
                                                   const float* __restrict__ mi,
                                                   const float* __restrict__ ss,
                                                   float* __restrict__ aout,
                                                   float* __restrict__ lam,
                                                   float* __restrict__ varPart) {
  __shared__ float Xs[2][ND][PAD];
  __shared__ float vred[2];
  int tid = threadIdx.x;
  int lane = tid & 63;
  int wv = tid >> 6;
  float (&X)[ND][PAD] = Xs[wv];
  int wid = blockIdx.x * 2 + wv;
  int nw = gridDim.x * 2;
  float varacc = 0.f;

  for (int i = wid; i < NB; i += nw) {
    for (int r2 = 0; r2 < ND; ++r2) X[r2][lane] = x[(size_t)i * NN + r2 * ND + lane];
    float w_[ND];
#pragma unroll
    for (int r2 = 0; r2 < ND; ++r2) w_[r2] = 0.f;
    for (int a = 0; a < ND; ++a) {
      float xa = X[a][lane];
#pragma unroll
      for (int r2 = 0; r2 < ND; ++r2) w_[r2] = fmaf(mi[a * ND + r2], xa, w_[r2]);
    }
#pragma unroll
    for (int r2 = 0; r2 < ND; ++r2) X[r2][lane] = w_[r2];
#pragma unroll
    for (int r2 = 0; r2 < ND; ++r2) w_[r2] = 0.f;
    for (int a = 0; a < ND; ++a) {
      float sa = mi[a * ND + lane];
#pragma unroll
      for (int r2 = 0; r2 < ND; ++r2) w_[r2] = fmaf(X[r2][a], sa, w_[r2]);
    }
    jacobi1s(w_, lane);
    float s2 = 0.f;
#pragma unroll
    for (int r2 = 0; r2 < ND; ++r2) s2 = fmaf(w_[r2], w_[r2], s2);
    float sig = sqrtf(fmaxf(s2, 1e-38f));
    float inv = 1.f / sig;
    lam[(size_t)i * ND + lane] = sig;
    float lg = logf(sig);
    varacc = fmaf(lg, lg, varacc);
#pragma unroll
    for (int r2 = 0; r2 < ND; ++r2) X[r2][lane] = w_[r2] * inv;  // U
    // Aout = ss * U   (ss symmetric) -> column `lane`
    float acc[ND];
#pragma unroll
    for (int r2 = 0; r2 < ND; ++r2) acc[r2] = 0.f;
    for (int a = 0; a < ND; ++a) {
      float ua = X[a][lane];
#pragma unroll
      for (int r2 = 0; r2 < ND; ++r2) acc[r2] = fmaf(ss[a * ND + r2], ua, acc[r2]);
    }
#pragma unroll
    for (int r2 = 0; r2 < ND; ++r2)
      aout[(size_t)i * NN + r2 * ND + lane] = acc[r2];
  }
  for (int o = 32; o; o >>= 1) varacc += __shfl_down(varacc, o);
  if (lane == 0) vred[wv] = varacc;
  __syncthreads();
  if (tid == 0) varPart[blockIdx.x] = vred[0] + vred[1];
}

__global__ __launch_bounds__(64) void k_pfinal(const float* __restrict__ varPart,
                                               const float* __restrict__ scale,
                                               float* __restrict__ pout) {
  int tid = threadIdx.x;
  float s = 0.f;
  for (int i = tid; i < 1024; i += 64) s += varPart[i];
  for (int o = 32; o; o >>= 1) s += __shfl_down(s, o);
  if (tid == 0) {
    float var = s * (1.f / (float)NB);
    float sd = sqrtf(var);
    pout[0] = scale[0] / (sd + 1e-5f);
  }
}

// out_i = A_i diag(lam^p) A_i^T  (A read from d_out, result overwrites it)
__global__ __launch_bounds__(256) void k_stage5(const float* __restrict__ ain,
                                                const float* __restrict__ lam,
                                                const float* __restrict__ pws,
                                                float* __restrict__ out) {
  __shared__ float Ab[ND][PAD];
  __shared__ float lp[ND];
  int tid = threadIdx.x;
  int i = blockIdx.x;
  for (int e = tid; e < NN; e += 256) Ab[e >> 6][e & 63] = ain[(size_t)i * NN + e];
  if (tid < ND) {
    float p = pws[0];
    lp[tid] = powf(lam[(size_t)i * ND + tid], p);
  }
  __syncthreads();
  int c = tid & 63, wq = tid >> 6;
  float acc[16];
#pragma unroll
  for (int k = 0; k < 16; ++k) acc[k] = 0.f;
  for (int j = 0; j < ND; ++j) {
    float m = lp[j] * Ab[c][j];
#pragma unroll
    for (int k = 0; k < 16; ++k) acc[k] = fmaf(Ab[wq + 4 * k][j], m, acc[k]);
  }
#pragma unroll
  for (int k = 0; k < 16; ++k)
    out[(size_t)i * NN + (wq + 4 * k) * ND + c] = acc[k];
}

// ---------------------------------------------------------------------------
extern "C" void kernel_launch(void* const* d_in, const int* in_sizes, int n_in,
                              void* d_out, int out_size, void* d_ws, size_t ws_size,
                              hipStream_t stream) {
  const float* x     = (const float*)d_in[0];
  const float* shift = (const float*)d_in[1];
  const float* scale = (const float*)d_in[2];
  float* out = (float*)d_out;
  float* ws  = (float*)d_ws;
  (void)in_sizes; (void)n_in; (void)out_size;

  size_t wsf = ws_size / 4;
  int G2 = 1024;
  if (OFF_TPART + (size_t)G2 * NN > wsf) {
    size_t avail = (wsf > OFF_TPART) ? (wsf - OFF_TPART) / NN : 1;
    if (avail < 1) avail = 1;
    if (avail < (size_t)G2) G2 = (int)avail;
  }

  k_mean_part<<<dim3(16, 32), 256, 0, stream>>>(x, ws + OFF_MEANPART);
  k_mean_final<<<16, 256, 0, stream>>>(ws + OFF_MEANPART, ws + OFF_MEANA);
  k_prep1<<<2, 256, 0, stream>>>(ws + OFF_MEANA, shift, ws + OFF_S, ws + OFF_SI,
                                 ws + OFF_SS);
  k_stage2<<<G2, 128, 0, stream>>>(x, ws + OFF_SI, ws + OFF_TPART, G2);
  k_reduce_t<<<16, 256, 0, stream>>>(ws + OFF_TPART, ws + OFF_TBAR, G2);
  k_prep2<<<1, 256, 0, stream>>>(ws + OFF_TBAR, ws + OFF_S, ws + OFF_MI);
  k_stage3<<<1024, 128, 0, stream>>>(x, ws + OFF_MI, ws + OFF_SS, out,
                                     ws + OFF_LAM, ws + OFF_VARPART);
  k_pfinal<<<1, 64, 0, stream>>>(ws + OFF_VARPART, scale, ws + OFF_P);
  k_stage5<<<8192, 256, 0, stream>>>(out, ws + OFF_LAM, ws + OFF_P, out);
}